// Round 5
// baseline (439.189 us; speedup 1.0000x reference)
//
#include <hip/hip_runtime.h>
#include <math.h>

typedef unsigned char  uchar_t;
typedef unsigned int   uint32;
typedef __attribute__((ext_vector_type(4)))  int   i32x4;
typedef __attribute__((ext_vector_type(8)))  int   i32x8;
typedef __attribute__((ext_vector_type(16))) float f32x16;

#define EMB     512
#define NROWS   8192
#define NITEMS  4096
#define NSPLIT  16
#define CPS     512
#define CTILE   128
#define QTILE   128
#define NCT     4
#define LDEPTH  8
#define KEEP    8
#define NRESC   16

__device__ inline uint32 packkey(float v, int idx) {
    uint32 u = __float_as_uint(v);
    uint32 s = u ^ ((u & 0x80000000u) ? 0xFFFFFFFFu : 0x80000000u);
    return (s & 0xFFFFE000u) | ((uint32)idx ^ 0x1FFFu);
}

// ---------------- Phase A: fp64 norms + normalized fp8(e4m3, x16) plane ----------------
__global__ void prep_kernel(const float* __restrict__ E,
                            uchar_t* __restrict__ Xq, double* __restrict__ invd) {
    const int row  = blockIdx.x * 4 + (threadIdx.x >> 6);
    const int lane = threadIdx.x & 63;
    const float4* p = (const float4*)(E + (size_t)row * EMB);
    float4 f0 = p[lane];
    float4 f1 = p[lane + 64];
    double s = (double)f0.x*f0.x + (double)f0.y*f0.y + (double)f0.z*f0.z + (double)f0.w*f0.w
             + (double)f1.x*f1.x + (double)f1.y*f1.y + (double)f1.z*f1.z + (double)f1.w*f1.w;
#pragma unroll
    for (int m = 32; m > 0; m >>= 1) s += __shfl_xor(s, m);
    const double inv = 1.0 / sqrt(s);
    if (lane == 0) invd[row] = inv;
    const float sc = (float)inv * 16.0f;
    int w0 = 0, w1 = 0;
    w0 = __builtin_amdgcn_cvt_pk_fp8_f32(f0.x * sc, f0.y * sc, w0, false);
    w0 = __builtin_amdgcn_cvt_pk_fp8_f32(f0.z * sc, f0.w * sc, w0, true);
    w1 = __builtin_amdgcn_cvt_pk_fp8_f32(f1.x * sc, f1.y * sc, w1, false);
    w1 = __builtin_amdgcn_cvt_pk_fp8_f32(f1.z * sc, f1.w * sc, w1, true);
    ((int2*)(Xq + (size_t)row * EMB))[lane] = make_int2(w0, w1);
}

// ---------------- Phase B: MX-fp8 32x32x64 MFMA, fragments direct from L2 ----------------
// R5: R4 was latency-bound (VGPR=52 proved only ONE fragment set live -> serial
// load->wait->mfma chain, 300cy L2 latency exposed per ks). Fix: full ks unroll
// with TWO named fragment sets (X/Y) alternating; loads for ks+1 issued before
// MFMAs of ks -> counted vmcnt, latency hidden. Cross-ct prefetch at ks=7.
// Indices/epilogue/merge identical to verified R4.
__global__ __launch_bounds__(512, 4) void sim_topk_mfma(
    const uchar_t* __restrict__ Xq, uint32* __restrict__ keys_out) {

    __shared__ uint32 mk[128][73];   // 128 queries x 8 sublists x 9 (8 keys + sentinel)

    const int t     = threadIdx.x;
    const int lane  = t & 63;
    const int wave  = t >> 6;      // 0..7
    const int wm    = wave >> 1;   // 0..3 : candidate sub-tile (32 rows)
    const int wn    = wave & 1;    // 0..1 : query half (64 cols)
    const int rb    = blockIdx.x >> 4;
    const int split = blockIdx.x & 15;
    const int qbase = rb * QTILE;
    const int l31   = lane & 31;
    const int l5    = lane >> 5;

    // A frag: row = split*CPS + ct*CTILE + wm*32 + l31, k-bytes l5*32 + ks*64 (+0/+16)
    // B frag fc: row = qbase + wn*64 + fc*32 + l31,     k-bytes l5*32 + ks*64 (+0/+16)
    const uchar_t* pa  = Xq + (size_t)(split * CPS + wm * 32 + l31) * EMB + (l5 << 5);
    const uchar_t* pb0 = Xq + (size_t)(qbase + wn * 64 + l31) * EMB + (l5 << 5);
    const uchar_t* pb1 = pb0 + (size_t)32 * EMB;

    uint32 tv[2][LDEPTH];
#pragma unroll
    for (int fc = 0; fc < 2; ++fc)
#pragma unroll
        for (int d = 0; d < LDEPTH; ++d) tv[fc][d] = 0u;

    f32x16 acc[2];
#pragma unroll
    for (int fc = 0; fc < 2; ++fc)
#pragma unroll
        for (int q = 0; q < 16; ++q) acc[fc][q] = 0.f;

    union U8 { i32x8 v8; struct { i32x4 lo; i32x4 hi; } h; };

    // Two named fragment sets -> both stay live (static names; no runtime indexing)
    U8 aX, b0X, b1X, aY, b0Y, b1Y;

#define LOADSET(A_, B0_, B1_, PA_, KO_)                         \
    do {                                                        \
        A_.h.lo  = *(const i32x4*)((PA_) + (KO_));              \
        A_.h.hi  = *(const i32x4*)((PA_) + (KO_) + 16);         \
        B0_.h.lo = *(const i32x4*)(pb0 + (KO_));                \
        B0_.h.hi = *(const i32x4*)(pb0 + (KO_) + 16);           \
        B1_.h.lo = *(const i32x4*)(pb1 + (KO_));                \
        B1_.h.hi = *(const i32x4*)(pb1 + (KO_) + 16);           \
    } while (0)

#define MFMA2(A_, B0_, B1_)                                                  \
    do {                                                                     \
        acc[0] = __builtin_amdgcn_mfma_scale_f32_32x32x64_f8f6f4(            \
            A_.v8, B0_.v8, acc[0], 0, 0, 0, 0x7F7F7F7F, 0, 0x7F7F7F7F);      \
        acc[1] = __builtin_amdgcn_mfma_scale_f32_32x32x64_f8f6f4(            \
            A_.v8, B1_.v8, acc[1], 0, 0, 0, 0x7F7F7F7F, 0, 0x7F7F7F7F);      \
    } while (0)

    LOADSET(aX, b0X, b1X, pa, 0);   // prologue: ks 0 of ct 0

#pragma unroll 1
    for (int ct = 0; ct < NCT; ++ct) {
        // next ct's A base (last ct: reload own base; valid reads, discarded)
        const uchar_t* pan = (ct < NCT - 1) ? (pa + (size_t)CTILE * EMB) : pa;

#pragma unroll
        for (int kp = 0; kp < 4; ++kp) {
            const int ko1 = (2 * kp + 1) * 64;
            // even ks (2kp): compute X, prefetch Y for ks 2kp+1
            LOADSET(aY, b0Y, b1Y, pa, ko1);
            MFMA2(aX, b0X, b1X);
            // odd ks (2kp+1): compute Y, prefetch X for ks 2kp+2 (or next-ct ks0)
            if (kp < 3) {
                LOADSET(aX, b0X, b1X, pa, ko1 + 64);
            } else {
                LOADSET(aX, b0X, b1X, pan, 0);
            }
            MFMA2(aY, b0Y, b1Y);
        }

        // ---- register-only epilogue: packed-key insert into per-lane top-8 ----
        const int cand0 = split * CPS + ct * CTILE;
#pragma unroll
        for (int fc = 0; fc < 2; ++fc) {
            float t0 = fmaxf(fmaxf(acc[fc][0],  acc[fc][1]),  acc[fc][2]);
            float t1 = fmaxf(fmaxf(acc[fc][3],  acc[fc][4]),  acc[fc][5]);
            float t2 = fmaxf(fmaxf(acc[fc][6],  acc[fc][7]),  acc[fc][8]);
            float t3 = fmaxf(fmaxf(acc[fc][9],  acc[fc][10]), acc[fc][11]);
            float t4 = fmaxf(fmaxf(acc[fc][12], acc[fc][13]), acc[fc][14]);
            float mx = fmaxf(fmaxf(fmaxf(t0, t1), t2),
                             fmaxf(fmaxf(t3, t4), acc[fc][15]));
            if (packkey(mx, 0) > tv[fc][LDEPTH - 1]) {
                const int jb = cand0 + wm * 32 + (l5 << 2);
#pragma unroll
                for (int reg = 0; reg < 16; ++reg) {
                    const int ci = jb + (reg & 3) + ((reg >> 2) << 3);
                    uint32 key = packkey(acc[fc][reg], ci);
                    if (key > tv[fc][LDEPTH - 1]) {
                        uint32 c2 = key;
#pragma unroll
                        for (int d = 0; d < LDEPTH; ++d) {
                            const uint32 a  = tv[fc][d];
                            const uint32 hi = a > c2 ? a : c2;
                            c2              = a > c2 ? c2 : a;
                            tv[fc][d] = hi;
                        }
                    }
                }
            }
#pragma unroll
            for (int q = 0; q < 16; ++q) acc[fc][q] = 0.f;
        }

        pa = pan;
    }

#undef LOADSET
#undef MFMA2

    // ---- merge 8 lane-lists per query, emit sorted top-8 keys ----
#pragma unroll
    for (int fc = 0; fc < 2; ++fc) {
        const int col = wn * 64 + fc * 32 + l31;
        const int sl  = wm * 2 + l5;      // 0..7
#pragma unroll
        for (int d = 0; d < LDEPTH; ++d) mk[col][sl * 9 + d] = tv[fc][d];
        mk[col][sl * 9 + 8] = 0u;         // sentinel: merge needs no bounds check
    }
    __syncthreads();
    if (t < 128) {
        int p[8] = {0, 0, 0, 0, 0, 0, 0, 0};
        const size_t base2 = ((size_t)(qbase + t) * NSPLIT + split) * KEEP;
#pragma unroll 1
        for (int sel = 0; sel < KEEP; ++sel) {
            uint32 bk = 0; int bl = 0;
#pragma unroll
            for (int l = 0; l < 8; ++l) {
                uint32 k = mk[t][l * 9 + p[l]];
                if (k > bk) { bk = k; bl = l; }
            }
#pragma unroll
            for (int l = 0; l < 8; ++l) p[l] += (bl == l);   // static-indexed update
            keys_out[base2 + sel] = bk;
        }
    }
}

// ---------------- Phase C: one row per block — rank-select top-16 + fp64 rescue ----------------
__global__ __launch_bounds__(256) void rescue_kernel(
    const float* __restrict__ E, const double* __restrict__ invd,
    const uint32* __restrict__ keys,
    const int* __restrict__ n_users, const int* __restrict__ n_entitys,
    const int* __restrict__ interactions, float* __restrict__ out) {

    __shared__ uint32 skeys[128];
    __shared__ float4 sq[128];
    __shared__ int    scand[NRESC];
    __shared__ double sd[NRESC];
    __shared__ int    sci[NRESC];
    __shared__ float  smemb[NRESC];
    __shared__ double contrib[8];

    const int t   = threadIdx.x;
    const int row = blockIdx.x;

    if (t < 128) {
        skeys[t] = keys[(size_t)row * 128 + t];
        sq[t]    = ((const float4*)(E + (size_t)row * EMB))[t];
    }
    if (t < NRESC) scand[t] = 0;      // poison-proof
    if (t < 8)     contrib[t] = 0.0;
    __syncthreads();

    if (t < 128) {
        const uint32 k = skeys[t];
        int r = 0;
#pragma unroll 16
        for (int j = 0; j < 128; ++j) {
            const uint32 kj = skeys[j];
            r += (kj > k) || (kj == k && j < t);
        }
        if (r < NRESC) scand[r] = (int)((k & 0x1FFFu) ^ 0x1FFFu);
    }
    __syncthreads();

    const int g    = t >> 4;
    const int l16  = t & 15;
    const int cand = scand[g] & (NROWS - 1);
    const float4* C = (const float4*)(E + (size_t)cand * EMB);
    double acc = 0.0;
#pragma unroll
    for (int j = 0; j < 8; ++j) {
        float4 c = C[l16 + 16 * j];
        float4 q = sq[l16 + 16 * j];
        acc += (double)q.x * c.x + (double)q.y * c.y
             + (double)q.z * c.z + (double)q.w * c.w;
    }
#pragma unroll
    for (int m = 8; m >= 1; m >>= 1) acc += __shfl_xor(acc, m, 16);

    const int ent = n_entitys[row];
    if (l16 == 0) { sd[g] = acc * invd[row] * invd[cand]; sci[g] = cand; }
    if (l16 == 1) {
        const int uid = n_users[cand];
        smemb[g] = (float)interactions[(size_t)uid * NITEMS + ent];
    }
    __syncthreads();

    if (t < NRESC) {
        const double v  = sd[t];
        const int    ci = sci[t];
        int r = 0;
#pragma unroll
        for (int j = 0; j < NRESC; ++j) {
            const double vj = sd[j];
            const int    cj = sci[j];
            r += (vj > v) || (vj == v && (cj < ci || (cj == ci && j < t)));
        }
        if (r < 6) contrib[r] = v * (double)smemb[t];
    }
    __syncthreads();
    if (t == 0) {
        const double sum = contrib[0] + contrib[1] + contrib[2]
                         + contrib[3] + contrib[4] + contrib[5];
        out[row] = (float)(sum * (1.0 / 6.0));
    }
}

extern "C" void kernel_launch(void* const* d_in, const int* in_sizes, int n_in,
                              void* d_out, int out_size, void* d_ws, size_t ws_size,
                              hipStream_t stream) {
    const float* E            = (const float*)d_in[0];
    const int*   n_users      = (const int*)d_in[1];
    const int*   n_entitys    = (const int*)d_in[2];
    const int*   interactions = (const int*)d_in[3];
    float*       out          = (float*)d_out;

    uchar_t* Xq   = (uchar_t*)d_ws;
    double*  invd = (double*)(Xq + (size_t)NROWS * EMB);
    uint32*  keys = (uint32*)(invd + NROWS);

    prep_kernel<<<NROWS / 4, 256, 0, stream>>>(E, Xq, invd);
    sim_topk_mfma<<<(NROWS / QTILE) * NSPLIT, 512, 0, stream>>>(Xq, keys);
    rescue_kernel<<<NROWS, 256, 0, stream>>>(E, invd, keys, n_users, n_entitys,
                                             interactions, out);
}

// Round 6
// 317.171 us; speedup vs baseline: 1.3847x; 1.3847x over previous
//
#include <hip/hip_runtime.h>
#include <math.h>

typedef unsigned char  uchar_t;
typedef unsigned int   uint32;
typedef __attribute__((ext_vector_type(2)))  int   i32x2;
typedef __attribute__((ext_vector_type(8)))  int   i32x8;
typedef __attribute__((ext_vector_type(16))) float f32x16;

#define EMB     512
#define NROWS   8192
#define NITEMS  4096
#define NSPLIT  16
#define CPS     512
#define CTILE   128
#define QTILE   128
#define NSTEPS  32
#define LDEPTH  8
#define KEEP    8
#define NRESC   16

// Proven form: LDS dest = base + lane*16, imm offset stays 0.
#define GLOAD_LDS(gp, lp) __builtin_amdgcn_global_load_lds( \
    (const __attribute__((address_space(1))) void*)(gp),    \
    (__attribute__((address_space(3))) void*)(lp), 16, 0, 0)

__device__ inline uint32 packkey(float v, int idx) {
    uint32 u = __float_as_uint(v);
    uint32 s = u ^ ((u & 0x80000000u) ? 0xFFFFFFFFu : 0x80000000u);
    return (s & 0xFFFFE000u) | ((uint32)idx ^ 0x1FFFu);
}

// ---------------- Phase A: fp64 norms + fp8 plane in word-pair-interleaved tiles ----
// Xq layout (R6): 2KB block per (rowgroup g=row/32, kslab s=kbyte/64), block-major
//   addr = (g*8 + s)*2048 + j8*256 + (row&31)*8 + b   (j8 = (kbyte%64)/8, b = kbyte%8)
// Row-transposed at 8B granularity -> ds_read_b64 fragment reads are near conflict-free,
// while DMA staging remains a LINEAR 1KB copy (global_load_lds compatible).
__global__ void prep_kernel(const float* __restrict__ E,
                            uchar_t* __restrict__ Xq, double* __restrict__ invd) {
    const int row  = blockIdx.x * 4 + (threadIdx.x >> 6);
    const int lane = threadIdx.x & 63;
    const float4* p = (const float4*)(E + (size_t)row * EMB);
    float4 f0 = p[lane];
    float4 f1 = p[lane + 64];
    double s = (double)f0.x*f0.x + (double)f0.y*f0.y + (double)f0.z*f0.z + (double)f0.w*f0.w
             + (double)f1.x*f1.x + (double)f1.y*f1.y + (double)f1.z*f1.z + (double)f1.w*f1.w;
#pragma unroll
    for (int m = 32; m > 0; m >>= 1) s += __shfl_xor(s, m);
    const double inv = 1.0 / sqrt(s);
    if (lane == 0) invd[row] = inv;
    const float sc = (float)inv * 16.0f;
    int w0 = 0, w1 = 0;
    w0 = __builtin_amdgcn_cvt_pk_fp8_f32(f0.x * sc, f0.y * sc, w0, false);
    w0 = __builtin_amdgcn_cvt_pk_fp8_f32(f0.z * sc, f0.w * sc, w0, true);
    w1 = __builtin_amdgcn_cvt_pk_fp8_f32(f1.x * sc, f1.y * sc, w1, false);
    w1 = __builtin_amdgcn_cvt_pk_fp8_f32(f1.z * sc, f1.w * sc, w1, true);
    // lane's 8 bytes = permuted-k bytes [8*lane, 8*lane+8) of this row (same permutation
    // for all rows -> dot products unchanged). Slot: kslab = lane>>3, j8 = lane&7.
    const int g  = row >> 5, l = row & 31;
    const int ks = lane >> 3, j8 = lane & 7;
    *(int2*)(Xq + ((size_t)(g * 8 + ks)) * 2048 + j8 * 256 + l * 8) = make_int2(w0, w1);
}

// ---------------- Phase B: dbuf MX-fp8 32x32x64 MFMA, 128x128 tile (R2 structure) ----
// R6 = verified R2 (103us) + interleaved Xq + 4x ds_read_b64 fragment reads.
// R2's measured cost: 24 extra conflict cycles per ds_read_b128 (16B lane stride ->
// bank depends on lane%8 only -> 8-way). b64 at 8B lane stride -> <=4 lanes/bank.
// Fragment bytes delivered to MFMA are bit-identical to R2; epilogue/merge unchanged.
__global__ __launch_bounds__(256, 4) void sim_topk_mfma(
    const uchar_t* __restrict__ Xq, uint32* __restrict__ keys_out) {

    __shared__ union {
        struct { uchar_t A[2][8192]; uchar_t B[2][8192]; } s;  // 32 KB dbuf staging
        struct { uint32 mk[128][37]; } m;                       // 18.9 KB merge
    } sh;

    const int t     = threadIdx.x;
    const int lane  = t & 63;
    const int wave  = t >> 6;
    const int wm    = wave >> 1;
    const int wn    = wave & 1;
    const int rb    = blockIdx.x >> 4;
    const int split = blockIdx.x & 15;
    const int qbase = rb * QTILE;
    const int l31   = lane & 31;
    const int l5    = lane >> 5;

    // 16 DMAs/step = 8 A-blocks-halves + 8 B. Waves 0,1 stage A; 2,3 stage B.
    // Wave's chunk c (0..3): rowgroup-block (2*wj + (c>>1)), half (c&1); 1KB linear copy.
    const bool isA = (wave < 2);
    const int  wj  = wave & 1;
    const int  g0  = (isA ? split * CPS : qbase) >> 5;    // tile start rowgroup
    const uchar_t* cur[4];
#pragma unroll
    for (int c = 0; c < 4; ++c) {
        const int g = g0 + wj * 2 + (c >> 1);
        cur[c] = Xq + ((size_t)g * 8) * 2048 + (c & 1) * 1024 + lane * 16;   // ks=0
    }
    // per-step: +2048 (next kslab); at ct boundary: A +4 rowgroups & kslab reset,
    // B kslab reset only.
    const long incA_ct = (long)4 * 8 * 2048 - 7 * 2048;   // +51200
    const long incB_ct = -(long)(7 * 2048);               // -14336

    auto stage = [&](int buf) {
        uchar_t* bp = (isA ? sh.s.A[buf] : sh.s.B[buf]) + wj * 4096;
#pragma unroll
        for (int c = 0; c < 4; ++c) GLOAD_LDS(cur[c], bp + c * 1024);
    };

    uint32 tv[2][LDEPTH];
#pragma unroll
    for (int fc = 0; fc < 2; ++fc)
#pragma unroll
        for (int d = 0; d < LDEPTH; ++d) tv[fc][d] = 0u;

    f32x16 acc[2][2];
#pragma unroll
    for (int fr = 0; fr < 2; ++fr)
#pragma unroll
        for (int fc = 0; fc < 2; ++fc)
#pragma unroll
            for (int q = 0; q < 16; ++q) acc[fr][fc][q] = 0.f;

    stage(0);   // prologue: step 0

    // fragment read base within a staged 8KB panel: block*2048 + l5*1024 + l31*8,
    // 4x ds_read_b64 at imm offsets jj*256 (j8 = l5*4 + jj)
    const int fo = (l5 << 10) + (l31 << 3);

    union U8 { i32x8 v8; i32x2 q[4]; };

#pragma unroll 1
    for (int s = 0; s < NSTEPS; ++s) {
        const int buf = s & 1;

        __syncthreads();   // drains this step's DMA (issued one compute-phase ago)

        if (s + 1 < NSTEPS) {
            const bool newct = ((s + 1) & 7) == 0;
            const long d = isA ? (newct ? incA_ct : 2048)
                               : (newct ? incB_ct : 2048);
#pragma unroll
            for (int c = 0; c < 4; ++c) cur[c] += d;
            stage((s + 1) & 1);
        }

        U8 a0, a1, b0, b1;
        {
            const uchar_t* Ab = sh.s.A[buf] + (wm * 4096) + fo;
            const uchar_t* Bb = sh.s.B[buf] + (wn * 4096) + fo;
#pragma unroll
            for (int jj = 0; jj < 4; ++jj) {
                a0.q[jj] = *(const i32x2*)(Ab + jj * 256);
                a1.q[jj] = *(const i32x2*)(Ab + 2048 + jj * 256);
                b0.q[jj] = *(const i32x2*)(Bb + jj * 256);
                b1.q[jj] = *(const i32x2*)(Bb + 2048 + jj * 256);
            }
        }

        acc[0][0] = __builtin_amdgcn_mfma_scale_f32_32x32x64_f8f6f4(
            a0.v8, b0.v8, acc[0][0], 0, 0, 0, 0x7F7F7F7F, 0, 0x7F7F7F7F);
        acc[1][0] = __builtin_amdgcn_mfma_scale_f32_32x32x64_f8f6f4(
            a1.v8, b0.v8, acc[1][0], 0, 0, 0, 0x7F7F7F7F, 0, 0x7F7F7F7F);
        acc[0][1] = __builtin_amdgcn_mfma_scale_f32_32x32x64_f8f6f4(
            a0.v8, b1.v8, acc[0][1], 0, 0, 0, 0x7F7F7F7F, 0, 0x7F7F7F7F);
        acc[1][1] = __builtin_amdgcn_mfma_scale_f32_32x32x64_f8f6f4(
            a1.v8, b1.v8, acc[1][1], 0, 0, 0, 0x7F7F7F7F, 0, 0x7F7F7F7F);

        if ((s & 7) == 7) {
            // ---- register-only epilogue: packed-key insert into per-lane top-8 ----
            const int cand0 = split * CPS + (s >> 3) * CTILE;
#pragma unroll
            for (int fc = 0; fc < 2; ++fc) {
#pragma unroll
                for (int fr = 0; fr < 2; ++fr) {
                    float t0 = fmaxf(fmaxf(acc[fr][fc][0],  acc[fr][fc][1]),  acc[fr][fc][2]);
                    float t1 = fmaxf(fmaxf(acc[fr][fc][3],  acc[fr][fc][4]),  acc[fr][fc][5]);
                    float t2 = fmaxf(fmaxf(acc[fr][fc][6],  acc[fr][fc][7]),  acc[fr][fc][8]);
                    float t3 = fmaxf(fmaxf(acc[fr][fc][9],  acc[fr][fc][10]), acc[fr][fc][11]);
                    float t4 = fmaxf(fmaxf(acc[fr][fc][12], acc[fr][fc][13]), acc[fr][fc][14]);
                    float mx = fmaxf(fmaxf(fmaxf(t0, t1), t2),
                                     fmaxf(fmaxf(t3, t4), acc[fr][fc][15]));
                    if (packkey(mx, 0) > tv[fc][LDEPTH - 1]) {
                        const int jb = cand0 + wm * 64 + fr * 32 + (l5 << 2);
#pragma unroll
                        for (int reg = 0; reg < 16; ++reg) {
                            const int ci = jb + (reg & 3) + ((reg >> 2) << 3);
                            uint32 key = packkey(acc[fr][fc][reg], ci);
                            if (key > tv[fc][LDEPTH - 1]) {
                                uint32 c2 = key;
#pragma unroll
                                for (int d = 0; d < LDEPTH; ++d) {
                                    const uint32 a  = tv[fc][d];
                                    const uint32 hi = a > c2 ? a : c2;
                                    c2              = a > c2 ? c2 : a;
                                    tv[fc][d] = hi;
                                }
                            }
                        }
                    }
#pragma unroll
                    for (int q = 0; q < 16; ++q) acc[fr][fc][q] = 0.f;
                }
            }
        }
    }

    // ---- merge 4 lane-lists per query, emit sorted top-8 keys ----
    __syncthreads();
#pragma unroll
    for (int fc = 0; fc < 2; ++fc) {
        const int col = wn * 64 + fc * 32 + l31;
        const int sl  = wm * 2 + l5;
#pragma unroll
        for (int d = 0; d < LDEPTH; ++d) sh.m.mk[col][sl * 9 + d] = tv[fc][d];
        sh.m.mk[col][sl * 9 + 8] = 0u;   // sentinel: 4-pointer merge needs no bounds check
    }
    __syncthreads();
    if (t < 128) {
        int p[4] = {0, 0, 0, 0};
        const size_t base2 = ((size_t)(qbase + t) * NSPLIT + split) * KEEP;
#pragma unroll 1
        for (int sel = 0; sel < KEEP; ++sel) {
            uint32 bk = 0; int bl = 0;
#pragma unroll
            for (int l = 0; l < 4; ++l) {
                uint32 k = sh.m.mk[t][l * 9 + p[l]];
                if (k > bk) { bk = k; bl = l; }
            }
#pragma unroll
            for (int l = 0; l < 4; ++l) p[l] += (bl == l);
            keys_out[base2 + sel] = bk;
        }
    }
}

// ---------------- Phase C: one row per block — rank-select top-16 + fp64 rescue ----------------
__global__ __launch_bounds__(256) void rescue_kernel(
    const float* __restrict__ E, const double* __restrict__ invd,
    const uint32* __restrict__ keys,
    const int* __restrict__ n_users, const int* __restrict__ n_entitys,
    const int* __restrict__ interactions, float* __restrict__ out) {

    __shared__ uint32 skeys[128];
    __shared__ float4 sq[128];
    __shared__ int    scand[NRESC];
    __shared__ double sd[NRESC];
    __shared__ int    sci[NRESC];
    __shared__ float  smemb[NRESC];
    __shared__ double contrib[8];

    const int t   = threadIdx.x;
    const int row = blockIdx.x;

    if (t < 128) {
        skeys[t] = keys[(size_t)row * 128 + t];
        sq[t]    = ((const float4*)(E + (size_t)row * EMB))[t];
    }
    if (t < NRESC) scand[t] = 0;      // poison-proof
    if (t < 8)     contrib[t] = 0.0;
    __syncthreads();

    if (t < 128) {
        const uint32 k = skeys[t];
        int r = 0;
#pragma unroll 16
        for (int j = 0; j < 128; ++j) {
            const uint32 kj = skeys[j];
            r += (kj > k) || (kj == k && j < t);
        }
        if (r < NRESC) scand[r] = (int)((k & 0x1FFFu) ^ 0x1FFFu);
    }
    __syncthreads();

    const int g    = t >> 4;
    const int l16  = t & 15;
    const int cand = scand[g] & (NROWS - 1);
    const float4* C = (const float4*)(E + (size_t)cand * EMB);
    double acc = 0.0;
#pragma unroll
    for (int j = 0; j < 8; ++j) {
        float4 c = C[l16 + 16 * j];
        float4 q = sq[l16 + 16 * j];
        acc += (double)q.x * c.x + (double)q.y * c.y
             + (double)q.z * c.z + (double)q.w * c.w;
    }
#pragma unroll
    for (int m = 8; m >= 1; m >>= 1) acc += __shfl_xor(acc, m, 16);

    const int ent = n_entitys[row];
    if (l16 == 0) { sd[g] = acc * invd[row] * invd[cand]; sci[g] = cand; }
    if (l16 == 1) {
        const int uid = n_users[cand];
        smemb[g] = (float)interactions[(size_t)uid * NITEMS + ent];
    }
    __syncthreads();

    if (t < NRESC) {
        const double v  = sd[t];
        const int    ci = sci[t];
        int r = 0;
#pragma unroll
        for (int j = 0; j < NRESC; ++j) {
            const double vj = sd[j];
            const int    cj = sci[j];
            r += (vj > v) || (vj == v && (cj < ci || (cj == ci && j < t)));
        }
        if (r < 6) contrib[r] = v * (double)smemb[t];
    }
    __syncthreads();
    if (t == 0) {
        const double sum = contrib[0] + contrib[1] + contrib[2]
                         + contrib[3] + contrib[4] + contrib[5];
        out[row] = (float)(sum * (1.0 / 6.0));
    }
}

extern "C" void kernel_launch(void* const* d_in, const int* in_sizes, int n_in,
                              void* d_out, int out_size, void* d_ws, size_t ws_size,
                              hipStream_t stream) {
    const float* E            = (const float*)d_in[0];
    const int*   n_users      = (const int*)d_in[1];
    const int*   n_entitys    = (const int*)d_in[2];
    const int*   interactions = (const int*)d_in[3];
    float*       out          = (float*)d_out;

    uchar_t* Xq   = (uchar_t*)d_ws;
    double*  invd = (double*)(Xq + (size_t)NROWS * EMB);
    uint32*  keys = (uint32*)(invd + NROWS);

    prep_kernel<<<NROWS / 4, 256, 0, stream>>>(E, Xq, invd);
    sim_topk_mfma<<<(NROWS / QTILE) * NSPLIT, 256, 0, stream>>>(Xq, keys);
    rescue_kernel<<<NROWS, 256, 0, stream>>>(E, invd, keys, n_users, n_entitys,
                                             interactions, out);
}

// Round 9
// 301.989 us; speedup vs baseline: 1.4543x; 1.0503x over previous
//
#include <hip/hip_runtime.h>
#include <math.h>

typedef unsigned char  uchar_t;
typedef unsigned int   uint32;
typedef __attribute__((ext_vector_type(2)))  int   i32x2;
typedef __attribute__((ext_vector_type(8)))  int   i32x8;
typedef __attribute__((ext_vector_type(16))) float f32x16;

#define EMB     512
#define NROWS   8192
#define NITEMS  4096
#define NSPLIT  16
#define CPS     512
#define CTILE   128
#define QTILE   128
#define NSTEPS  32
#define LDEPTH  8
#define KEEP    8
#define NRESC   16

// Proven form: LDS dest = base + lane*16, imm offset stays 0.
#define GLOAD_LDS(gp, lp) __builtin_amdgcn_global_load_lds( \
    (const __attribute__((address_space(1))) void*)(gp),    \
    (__attribute__((address_space(3))) void*)(lp), 16, 0, 0)

__device__ inline uint32 packkey(float v, int idx) {
    uint32 u = __float_as_uint(v);
    uint32 s = u ^ ((u & 0x80000000u) ? 0xFFFFFFFFu : 0x80000000u);
    return (s & 0xFFFFE000u) | ((uint32)idx ^ 0x1FFFu);
}

// ---------------- Phase A: fp64 norms + fp8 plane in word-pair-interleaved tiles ----
// Xq layout (R6, verified): 2KB block per (rowgroup g=row/32, kslab s=kbyte/64):
//   addr = (g*8 + s)*2048 + j8*256 + (row&31)*8 + b
__global__ void prep_kernel(const float* __restrict__ E,
                            uchar_t* __restrict__ Xq, double* __restrict__ invd) {
    const int row  = blockIdx.x * 4 + (threadIdx.x >> 6);
    const int lane = threadIdx.x & 63;
    const float4* p = (const float4*)(E + (size_t)row * EMB);
    float4 f0 = p[lane];
    float4 f1 = p[lane + 64];
    double s = (double)f0.x*f0.x + (double)f0.y*f0.y + (double)f0.z*f0.z + (double)f0.w*f0.w
             + (double)f1.x*f1.x + (double)f1.y*f1.y + (double)f1.z*f1.z + (double)f1.w*f1.w;
#pragma unroll
    for (int m = 32; m > 0; m >>= 1) s += __shfl_xor(s, m);
    const double inv = 1.0 / sqrt(s);
    if (lane == 0) invd[row] = inv;
    const float sc = (float)inv * 16.0f;
    int w0 = 0, w1 = 0;
    w0 = __builtin_amdgcn_cvt_pk_fp8_f32(f0.x * sc, f0.y * sc, w0, false);
    w0 = __builtin_amdgcn_cvt_pk_fp8_f32(f0.z * sc, f0.w * sc, w0, true);
    w1 = __builtin_amdgcn_cvt_pk_fp8_f32(f1.x * sc, f1.y * sc, w1, false);
    w1 = __builtin_amdgcn_cvt_pk_fp8_f32(f1.z * sc, f1.w * sc, w1, true);
    const int g  = row >> 5, l = row & 31;
    const int ks = lane >> 3, j8 = lane & 7;
    *(int2*)(Xq + ((size_t)(g * 8 + ks)) * 2048 + j8 * 256 + l * 8) = make_int2(w0, w1);
}

// ---------------- Phase B: dbuf MX-fp8 32x32x64 MFMA, 128x128 tile ----------------
// R9: byte-exact revert to the VERIFIED R6 kernel (317us, absmax 0).
// (R8's B-staged-once was wrong on first principles: a 2-deep dbuf holds the last
// 2 kslabs, not all 8 -- ct>=1 read ks6's data as ks0. Dead. lb(256,5) also dead:
// 5 waves/SIMD caps regs at ~96 < 64-reg acc + operands.)
__global__ __launch_bounds__(256, 4) void sim_topk_mfma(
    const uchar_t* __restrict__ Xq, uint32* __restrict__ keys_out) {

    __shared__ union {
        struct { uchar_t A[2][8192]; uchar_t B[2][8192]; } s;  // 32 KB dbuf staging
        struct { uint32 mk[128][37]; } m;                       // 18.9 KB merge
    } sh;

    const int t     = threadIdx.x;
    const int lane  = t & 63;
    const int wave  = t >> 6;
    const int wm    = wave >> 1;
    const int wn    = wave & 1;
    const int rb    = blockIdx.x >> 4;
    const int split = blockIdx.x & 15;
    const int qbase = rb * QTILE;
    const int l31   = lane & 31;
    const int l5    = lane >> 5;

    const bool isA = (wave < 2);
    const int  wj  = wave & 1;
    const int  g0  = (isA ? split * CPS : qbase) >> 5;
    const uchar_t* cur[4];
#pragma unroll
    for (int c = 0; c < 4; ++c) {
        const int g = g0 + wj * 2 + (c >> 1);
        cur[c] = Xq + ((size_t)g * 8) * 2048 + (c & 1) * 1024 + lane * 16;   // ks=0
    }
    const long incA_ct = (long)4 * 8 * 2048 - 7 * 2048;   // +51200
    const long incB_ct = -(long)(7 * 2048);               // -14336

    auto stage = [&](int buf) {
        uchar_t* bp = (isA ? sh.s.A[buf] : sh.s.B[buf]) + wj * 4096;
#pragma unroll
        for (int c = 0; c < 4; ++c) GLOAD_LDS(cur[c], bp + c * 1024);
    };

    uint32 tv[2][LDEPTH];
#pragma unroll
    for (int fc = 0; fc < 2; ++fc)
#pragma unroll
        for (int d = 0; d < LDEPTH; ++d) tv[fc][d] = 0u;

    f32x16 acc[2][2];
#pragma unroll
    for (int fr = 0; fr < 2; ++fr)
#pragma unroll
        for (int fc = 0; fc < 2; ++fc)
#pragma unroll
            for (int q = 0; q < 16; ++q) acc[fr][fc][q] = 0.f;

    stage(0);   // prologue: step 0

    const int fo = (l5 << 10) + (l31 << 3);

    union U8 { i32x8 v8; i32x2 q[4]; };

#pragma unroll 1
    for (int s = 0; s < NSTEPS; ++s) {
        const int buf = s & 1;

        __syncthreads();   // drains this step's DMA (issued one compute-phase ago)

        if (s + 1 < NSTEPS) {
            const bool newct = ((s + 1) & 7) == 0;
            const long d = isA ? (newct ? incA_ct : 2048)
                               : (newct ? incB_ct : 2048);
#pragma unroll
            for (int c = 0; c < 4; ++c) cur[c] += d;
            stage((s + 1) & 1);
        }

        U8 a0, a1, b0, b1;
        {
            const uchar_t* Ab = sh.s.A[buf] + (wm * 4096) + fo;
            const uchar_t* Bb = sh.s.B[buf] + (wn * 4096) + fo;
#pragma unroll
            for (int jj = 0; jj < 4; ++jj) {
                a0.q[jj] = *(const i32x2*)(Ab + jj * 256);
                a1.q[jj] = *(const i32x2*)(Ab + 2048 + jj * 256);
                b0.q[jj] = *(const i32x2*)(Bb + jj * 256);
                b1.q[jj] = *(const i32x2*)(Bb + 2048 + jj * 256);
            }
        }

        acc[0][0] = __builtin_amdgcn_mfma_scale_f32_32x32x64_f8f6f4(
            a0.v8, b0.v8, acc[0][0], 0, 0, 0, 0x7F7F7F7F, 0, 0x7F7F7F7F);
        acc[1][0] = __builtin_amdgcn_mfma_scale_f32_32x32x64_f8f6f4(
            a1.v8, b0.v8, acc[1][0], 0, 0, 0, 0x7F7F7F7F, 0, 0x7F7F7F7F);
        acc[0][1] = __builtin_amdgcn_mfma_scale_f32_32x32x64_f8f6f4(
            a0.v8, b1.v8, acc[0][1], 0, 0, 0, 0x7F7F7F7F, 0, 0x7F7F7F7F);
        acc[1][1] = __builtin_amdgcn_mfma_scale_f32_32x32x64_f8f6f4(
            a1.v8, b1.v8, acc[1][1], 0, 0, 0, 0x7F7F7F7F, 0, 0x7F7F7F7F);

        if ((s & 7) == 7) {
            const int cand0 = split * CPS + (s >> 3) * CTILE;
#pragma unroll
            for (int fc = 0; fc < 2; ++fc) {
#pragma unroll
                for (int fr = 0; fr < 2; ++fr) {
                    float t0 = fmaxf(fmaxf(acc[fr][fc][0],  acc[fr][fc][1]),  acc[fr][fc][2]);
                    float t1 = fmaxf(fmaxf(acc[fr][fc][3],  acc[fr][fc][4]),  acc[fr][fc][5]);
                    float t2 = fmaxf(fmaxf(acc[fr][fc][6],  acc[fr][fc][7]),  acc[fr][fc][8]);
                    float t3 = fmaxf(fmaxf(acc[fr][fc][9],  acc[fr][fc][10]), acc[fr][fc][11]);
                    float t4 = fmaxf(fmaxf(acc[fr][fc][12], acc[fr][fc][13]), acc[fr][fc][14]);
                    float mx = fmaxf(fmaxf(fmaxf(t0, t1), t2),
                                     fmaxf(fmaxf(t3, t4), acc[fr][fc][15]));
                    if (packkey(mx, 0) > tv[fc][LDEPTH - 1]) {
                        const int jb = cand0 + wm * 64 + fr * 32 + (l5 << 2);
#pragma unroll
                        for (int reg = 0; reg < 16; ++reg) {
                            const int ci = jb + (reg & 3) + ((reg >> 2) << 3);
                            uint32 key = packkey(acc[fr][fc][reg], ci);
                            if (key > tv[fc][LDEPTH - 1]) {
                                uint32 c2 = key;
#pragma unroll
                                for (int d = 0; d < LDEPTH; ++d) {
                                    const uint32 a  = tv[fc][d];
                                    const uint32 hi = a > c2 ? a : c2;
                                    c2              = a > c2 ? c2 : a;
                                    tv[fc][d] = hi;
                                }
                            }
                        }
                    }
#pragma unroll
                    for (int q = 0; q < 16; ++q) acc[fr][fc][q] = 0.f;
                }
            }
        }
    }

    // ---- merge 4 lane-lists per query, emit sorted top-8 keys ----
    __syncthreads();
#pragma unroll
    for (int fc = 0; fc < 2; ++fc) {
        const int col = wn * 64 + fc * 32 + l31;
        const int sl  = wm * 2 + l5;
#pragma unroll
        for (int d = 0; d < LDEPTH; ++d) sh.m.mk[col][sl * 9 + d] = tv[fc][d];
        sh.m.mk[col][sl * 9 + 8] = 0u;   // sentinel
    }
    __syncthreads();
    if (t < 128) {
        int p[4] = {0, 0, 0, 0};
        const size_t base2 = ((size_t)(qbase + t) * NSPLIT + split) * KEEP;
#pragma unroll 1
        for (int sel = 0; sel < KEEP; ++sel) {
            uint32 bk = 0; int bl = 0;
#pragma unroll
            for (int l = 0; l < 4; ++l) {
                uint32 k = sh.m.mk[t][l * 9 + p[l]];
                if (k > bk) { bk = k; bl = l; }
            }
#pragma unroll
            for (int l = 0; l < 4; ++l) p[l] += (bl == l);
            keys_out[base2 + sel] = bk;
        }
    }
}

// ---------------- Phase C: TWO rows per block — rank-select top-16 + fp64 rescue ----
// R9: grid 8192->4096; sub-block (t>>7) owns one row. Rank scan now uses all 256
// lanes (was 128); each 16-lane group computes 2 candidates in one fused loop
// (shared q loads, 16 gathers in flight). Per-row logic identical to verified R6.
__global__ __launch_bounds__(256) void rescue_kernel(
    const float* __restrict__ E, const double* __restrict__ invd,
    const uint32* __restrict__ keys,
    const int* __restrict__ n_users, const int* __restrict__ n_entitys,
    const int* __restrict__ interactions, float* __restrict__ out) {

    __shared__ uint32 skeys[2][128];
    __shared__ float4 sq[2][128];
    __shared__ int    scand[2][NRESC];
    __shared__ double sd[2][NRESC];
    __shared__ int    sci[2][NRESC];
    __shared__ float  smemb[2][NRESC];
    __shared__ double contrib[2][8];

    const int t   = threadIdx.x;
    const int sub = t >> 7;          // 0/1 : which row of the pair
    const int tt  = t & 127;
    const int row = blockIdx.x * 2 + sub;

    skeys[sub][tt] = keys[(size_t)row * 128 + tt];
    sq[sub][tt]    = ((const float4*)(E + (size_t)row * EMB))[tt];
    if (tt < NRESC) scand[sub][tt] = 0;      // poison-proof
    if (tt < 8)     contrib[sub][tt] = 0.0;
    __syncthreads();

    {
        const uint32 k = skeys[sub][tt];
        int r = 0;
#pragma unroll 16
        for (int j = 0; j < 128; ++j) {
            const uint32 kj = skeys[sub][j];
            r += (kj > k) || (kj == k && j < tt);
        }
        if (r < NRESC) scand[sub][r] = (int)((k & 0x1FFFu) ^ 0x1FFFu);
    }
    __syncthreads();

    const int g    = tt >> 4;        // 0..7 : candidate-pair group within this row
    const int l16  = tt & 15;
    const int c0   = scand[sub][g] & (NROWS - 1);
    const int c1   = scand[sub][g + 8] & (NROWS - 1);
    const float4* C0 = (const float4*)(E + (size_t)c0 * EMB);
    const float4* C1 = (const float4*)(E + (size_t)c1 * EMB);
    double a0 = 0.0, a1 = 0.0;
#pragma unroll
    for (int j = 0; j < 8; ++j) {
        float4 q  = sq[sub][l16 + 16 * j];
        float4 v0 = C0[l16 + 16 * j];
        float4 v1 = C1[l16 + 16 * j];
        a0 += (double)q.x * v0.x + (double)q.y * v0.y
            + (double)q.z * v0.z + (double)q.w * v0.w;
        a1 += (double)q.x * v1.x + (double)q.y * v1.y
            + (double)q.z * v1.z + (double)q.w * v1.w;
    }
#pragma unroll
    for (int m = 8; m >= 1; m >>= 1) {
        a0 += __shfl_xor(a0, m, 16);
        a1 += __shfl_xor(a1, m, 16);
    }

    const int ent = n_entitys[row];
    if (l16 == 0) {
        const double ir = invd[row];
        sd[sub][g]     = a0 * ir * invd[c0];
        sd[sub][g + 8] = a1 * ir * invd[c1];
        sci[sub][g]     = c0;
        sci[sub][g + 8] = c1;
    }
    if (l16 == 1) {
        smemb[sub][g]     = (float)interactions[(size_t)n_users[c0] * NITEMS + ent];
        smemb[sub][g + 8] = (float)interactions[(size_t)n_users[c1] * NITEMS + ent];
    }
    __syncthreads();

    if (tt < NRESC) {
        const double v  = sd[sub][tt];
        const int    ci = sci[sub][tt];
        int r = 0;
#pragma unroll
        for (int j = 0; j < NRESC; ++j) {
            const double vj = sd[sub][j];
            const int    cj = sci[sub][j];
            r += (vj > v) || (vj == v && (cj < ci || (cj == ci && j < tt)));
        }
        if (r < 6) contrib[sub][r] = v * (double)smemb[sub][tt];
    }
    __syncthreads();
    if (tt == 0) {
        const double sum = contrib[sub][0] + contrib[sub][1] + contrib[sub][2]
                         + contrib[sub][3] + contrib[sub][4] + contrib[sub][5];
        out[row] = (float)(sum * (1.0 / 6.0));
    }
}

extern "C" void kernel_launch(void* const* d_in, const int* in_sizes, int n_in,
                              void* d_out, int out_size, void* d_ws, size_t ws_size,
                              hipStream_t stream) {
    const float* E            = (const float*)d_in[0];
    const int*   n_users      = (const int*)d_in[1];
    const int*   n_entitys    = (const int*)d_in[2];
    const int*   interactions = (const int*)d_in[3];
    float*       out          = (float*)d_out;

    uchar_t* Xq   = (uchar_t*)d_ws;
    double*  invd = (double*)(Xq + (size_t)NROWS * EMB);
    uint32*  keys = (uint32*)(invd + NROWS);

    prep_kernel<<<NROWS / 4, 256, 0, stream>>>(E, Xq, invd);
    sim_topk_mfma<<<(NROWS / QTILE) * NSPLIT, 256, 0, stream>>>(Xq, keys);
    rescue_kernel<<<NROWS / 2, 256, 0, stream>>>(E, invd, keys, n_users, n_entitys,
                                                 interactions, out);
}